// Round 1
// baseline (221.418 us; speedup 1.0000x reference)
//
#include <hip/hip_runtime.h>
#include <math.h>

#define TS 160
#define FEATD 2048
#define HID 512
#define NC 20
#define NB 8

// ---------- Kernel 1: conv1d partials, K-split over feature dim ----------
// grid (16 m-tiles, 8 n-tiles, 4 ksplit), block 320 (20 tm x 16 tn), micro 4x4
__global__ __launch_bounds__(320) void k_conv1(const float* __restrict__ x,
                                               const float* __restrict__ w1,
                                               float* __restrict__ part) {
  const int mt = blockIdx.x;            // b*2 + t-half
  const int h0 = blockIdx.y * 64;
  const int kz = blockIdx.z;
  const int b  = mt >> 1;
  const int t0 = (mt & 1) * 80;
  const int tid = threadIdx.x;
  const int tn = tid & 15;              // 16 groups of 4 h
  const int tm = tid >> 4;              // 20 groups of 4 t

  __shared__ float Xs[82 * 33];         // rows t0-1 .. t0+80, 32 f, pad 33
  __shared__ float Ws[96 * 68];         // [f*3+k][h], pad 68 (16B aligned rows)

  float acc[4][4];
  #pragma unroll
  for (int i = 0; i < 4; ++i)
    #pragma unroll
    for (int j = 0; j < 4; ++j) acc[i][j] = 0.f;

  const float* xb = x + (size_t)b * TS * FEATD;

  for (int c32 = 0; c32 < 16; ++c32) {
    const int f0 = kz * 512 + c32 * 32;
    for (int e = tid; e < 82 * 32; e += 320) {
      int tr = e >> 5, f = e & 31;
      int t = t0 - 1 + tr;
      Xs[tr * 33 + f] = (t >= 0 && t < TS) ? xb[t * FEATD + f0 + f] : 0.f;
    }
    for (int e = tid; e < 96 * 64; e += 320) {
      int hh = e / 96, fk = e - hh * 96;
      Ws[fk * 68 + hh] = w1[(size_t)(h0 + hh) * (FEATD * 3) + f0 * 3 + fk];
    }
    __syncthreads();
    #pragma unroll 8
    for (int ff = 0; ff < 32; ++ff) {
      float a[6];
      #pragma unroll
      for (int r = 0; r < 6; ++r) a[r] = Xs[(tm * 4 + r) * 33 + ff];
      #pragma unroll
      for (int kk = 0; kk < 3; ++kk) {
        float4 bv = *(const float4*)&Ws[(ff * 3 + kk) * 68 + tn * 4];
        #pragma unroll
        for (int mi = 0; mi < 4; ++mi) {
          float av = a[mi + kk];
          acc[mi][0] += av * bv.x;
          acc[mi][1] += av * bv.y;
          acc[mi][2] += av * bv.z;
          acc[mi][3] += av * bv.w;
        }
      }
    }
    __syncthreads();
  }
  #pragma unroll
  for (int mi = 0; mi < 4; ++mi) {
    int t = t0 + tm * 4 + mi;
    float4 v = make_float4(acc[mi][0], acc[mi][1], acc[mi][2], acc[mi][3]);
    *(float4*)&part[(((size_t)kz * NB * TS) + (size_t)b * TS + t) * HID + h0 + tn * 4] = v;
  }
}

// ---------- Kernel 1b: sum K-split partials + bias + relu ----------
__global__ __launch_bounds__(256) void k_bias_relu(const float* __restrict__ part,
                                                   const float* __restrict__ bias,
                                                   float* __restrict__ feat) {
  const int idx = blockIdx.x * 256 + threadIdx.x;   // < 163840 float4s
  const float4* p = (const float4*)part;
  float4 v0 = p[idx];
  float4 v1 = p[163840 + idx];
  float4 v2 = p[2 * 163840 + idx];
  float4 v3 = p[3 * 163840 + idx];
  const float4 bb = ((const float4*)bias)[idx & 127];
  float4 o;
  o.x = fmaxf(v0.x + v1.x + v2.x + v3.x + bb.x, 0.f);
  o.y = fmaxf(v0.y + v1.y + v2.y + v3.y + bb.y, 0.f);
  o.z = fmaxf(v0.z + v1.z + v2.z + v3.z + bb.z, 0.f);
  o.w = fmaxf(v0.w + v1.w + v2.w + v3.w + bb.w, 0.f);
  ((float4*)feat)[idx] = o;
}

// ---------- Kernel 2: y_class (1x1 conv) + y_atn (k=3 conv + bias) ----------
// one wave per (b,t); grid 320 x 256
__global__ __launch_bounds__(256) void k_head(const float* __restrict__ feat,
                                              const float* __restrict__ wc,
                                              const float* __restrict__ wa,
                                              const float* __restrict__ ba,
                                              float* __restrict__ y_class,
                                              float* __restrict__ y_atn) {
  __shared__ float wcs[NC * HID];
  __shared__ float was[HID * 3];
  const int tid = threadIdx.x;
  for (int e = tid; e < NC * HID; e += 256) wcs[e] = wc[e];
  for (int e = tid; e < HID * 3; e += 256) was[e] = wa[e];
  __syncthreads();
  const int wave = blockIdx.x * 4 + (tid >> 6);
  const int lane = tid & 63;
  const int b = wave / TS, t = wave - b * TS;
  const float* frow = &feat[((size_t)b * TS + t) * HID];
  float fc[8], fm[8], fp[8];
  #pragma unroll
  for (int i2 = 0; i2 < 8; ++i2) {
    int h = lane + 64 * i2;
    fc[i2] = frow[h];
    fm[i2] = (t > 0)      ? frow[h - HID] : 0.f;
    fp[i2] = (t < TS - 1) ? frow[h + HID] : 0.f;
  }
  #pragma unroll 4
  for (int c = 0; c < NC; ++c) {
    float p = 0.f;
    #pragma unroll
    for (int i2 = 0; i2 < 8; ++i2) p += fc[i2] * wcs[c * HID + lane + 64 * i2];
    #pragma unroll
    for (int off = 32; off; off >>= 1) p += __shfl_xor(p, off);
    if (lane == 0) y_class[((size_t)b * NC + c) * TS + t] = p;
  }
  float p = 0.f;
  #pragma unroll
  for (int i2 = 0; i2 < 8; ++i2) {
    int h = lane + 64 * i2;
    p += fm[i2] * was[h * 3 + 0] + fc[i2] * was[h * 3 + 1] + fp[i2] * was[h * 3 + 2];
  }
  #pragma unroll
  for (int off = 32; off; off >>= 1) p += __shfl_xor(p, off);
  if (lane == 0) y_atn[b * TS + t] = p + ba[0];
}

// ---------- Kernel 3: attention pooling x_fg + y_fg ----------
// one block per b
__global__ __launch_bounds__(256) void k_fg(const float* __restrict__ feat,
                                            const float* __restrict__ y_atn,
                                            const float* __restrict__ wc,
                                            float* __restrict__ y_fg) {
  const int b = blockIdx.x;
  const int tid = threadIdx.x;
  __shared__ float sig[TS];
  __shared__ float red[4];
  __shared__ float xfg[HID];
  float s = 0.f;
  if (tid < TS) { s = 1.f / (1.f + expf(-y_atn[b * TS + tid])); sig[tid] = s; }
  float r = s;
  #pragma unroll
  for (int off = 32; off; off >>= 1) r += __shfl_xor(r, off);
  if ((tid & 63) == 0) red[tid >> 6] = r;
  __syncthreads();
  const float inv = 1.f / (red[0] + red[1] + red[2] + red[3] + 1e-8f);
  for (int h = tid; h < HID; h += 256) {
    float a = 0.f;
    for (int t = 0; t < TS; ++t) a += sig[t] * feat[((size_t)b * TS + t) * HID + h];
    xfg[h] = a * inv;
  }
  __syncthreads();
  const int wv = tid >> 6, lane = tid & 63;
  for (int c = wv; c < NC; c += 4) {
    float p = 0.f;
    #pragma unroll
    for (int i2 = 0; i2 < 8; ++i2) {
      int h = lane + 64 * i2;
      p += wc[c * HID + h] * xfg[h];
    }
    #pragma unroll
    for (int off = 32; off; off >>= 1) p += __shfl_xor(p, off);
    if (lane == 0) y_fg[b * NC + c] = p;
  }
}

// ---------- Kernel 4: boundary-matching via analytic sparse mask ----------
// thread per (b,i,j); grid 800 x 256
__global__ __launch_bounds__(256) void k_bmn(const float* __restrict__ y_class,
                                             float* __restrict__ bmn) {
  const int b = blockIdx.x / 100;
  const int blk = blockIdx.x - b * 100;
  const int tid = threadIdx.x;
  __shared__ float Y[TS * 24];          // [t][c], padded to 24 (16B-aligned rows)
  for (int e = tid; e < NC * TS; e += 256) {
    int c = e / TS, t = e - c * TS;
    Y[t * 24 + c] = y_class[((size_t)b * NC + c) * TS + t];
  }
  __syncthreads();
  const int idx = blk * 256 + tid;      // 0..25599
  const int i = idx / TS, j = idx - i * TS;
  float* ob = bmn + (size_t)b * 60 * TS * TS + (size_t)i * TS + j;
  const size_t cs = (size_t)TS * TS;
  if (j < i) {
    #pragma unroll 4
    for (int gc = 0; gc < 60; ++gc) ob[(size_t)gc * cs] = 0.f;
    return;
  }
  float ac[NC];
  auto step = [&](int k) {
    float pos = (float)(k * (j - i)) / 31.0f + (float)i;
    int dn = (int)pos;
    float frx = pos - (float)dn;
    int up = dn + (frx > 0.f ? 1 : 0);
    float wd = 1.f - frx;
    const float* yd = &Y[dn * 24];
    const float* yu = &Y[up * 24];
    #pragma unroll
    for (int c4 = 0; c4 < 5; ++c4) {
      float4 d4 = *(const float4*)(yd + c4 * 4);
      float4 u4 = *(const float4*)(yu + c4 * 4);
      ac[c4 * 4 + 0] += wd * d4.x + frx * u4.x;
      ac[c4 * 4 + 1] += wd * d4.y + frx * u4.y;
      ac[c4 * 4 + 2] += wd * d4.z + frx * u4.z;
      ac[c4 * 4 + 3] += wd * d4.w + frx * u4.w;
    }
  };
  // group 0: k 0..7 (mean of 8)
  #pragma unroll
  for (int c = 0; c < NC; ++c) ac[c] = 0.f;
  #pragma unroll 2
  for (int k = 0; k < 8; ++k) step(k);
  #pragma unroll
  for (int c = 0; c < NC; ++c) ob[(size_t)c * cs] = ac[c] * 0.125f;
  // group 1: k 8..23 (mean of 16)
  #pragma unroll
  for (int c = 0; c < NC; ++c) ac[c] = 0.f;
  #pragma unroll 2
  for (int k = 8; k < 24; ++k) step(k);
  #pragma unroll
  for (int c = 0; c < NC; ++c) ob[(size_t)(NC + c) * cs] = ac[c] * 0.0625f;
  // group 2: k 24..31 (mean of 8)
  #pragma unroll
  for (int c = 0; c < NC; ++c) ac[c] = 0.f;
  #pragma unroll 2
  for (int k = 24; k < 32; ++k) step(k);
  #pragma unroll
  for (int c = 0; c < NC; ++c) ob[(size_t)(2 * NC + c) * cs] = ac[c] * 0.125f;
}

extern "C" void kernel_launch(void* const* d_in, const int* in_sizes, int n_in,
                              void* d_out, int out_size, void* d_ws, size_t ws_size,
                              hipStream_t stream) {
  const float* x  = (const float*)d_in[0];
  // d_in[1] = sample_mask: unused (weights recomputed analytically)
  const float* w1 = (const float*)d_in[2];
  const float* b1 = (const float*)d_in[3];
  const float* wc = (const float*)d_in[4];
  const float* wa = (const float*)d_in[5];
  const float* ba = (const float*)d_in[6];

  float* out     = (float*)d_out;
  float* y_class = out;                       // [8,20,160]
  float* y_fg    = out + NB * NC * TS;        // [8,20,1]
  float* bmn     = out + NB * NC * TS + NB * NC;  // [8,60,160,160]

  float* part  = (float*)d_ws;                    // 4*1280*512 f32
  float* feat  = part + 4 * NB * TS * HID;        // 1280*512 f32
  float* y_atn = feat + NB * TS * HID;            // 1280 f32

  k_conv1<<<dim3(16, 8, 4), 320, 0, stream>>>(x, w1, part);
  k_bias_relu<<<640, 256, 0, stream>>>(part, b1, feat);
  k_head<<<320, 256, 0, stream>>>(feat, wc, wa, ba, y_class, y_atn);
  k_fg<<<8, 256, 0, stream>>>(feat, y_atn, wc, y_fg);
  k_bmn<<<800, 256, 0, stream>>>(y_class, bmn);
}

// Round 2
// 101.057 us; speedup vs baseline: 2.1910x; 2.1910x over previous
//
#include <hip/hip_runtime.h>
#include <math.h>

#define TS 160
#define FEATD 2048
#define HID 512
#define NC 20
#define NB 8

typedef __attribute__((ext_vector_type(8))) short bfrag;
typedef __attribute__((ext_vector_type(4))) float f32x4;

static __device__ __forceinline__ unsigned short f2bf(float f) {
  unsigned int u = __float_as_uint(f);
  unsigned int r = (u + 0x7FFFu + ((u >> 16) & 1u)) >> 16;
  return (unsigned short)r;
}

// ---------- cast x -> bf16, padded rows t=-1 and t=160 zeroed ----------
// xb layout [B][162][2048]; padded row pr maps to x row pr-1
__global__ __launch_bounds__(256) void k_cvt_x(const float* __restrict__ x,
                                               unsigned short* __restrict__ xb) {
  const int idx = blockIdx.x * 256 + threadIdx.x;   // 1296*256
  const int c = (idx & 255) * 8;
  const int row = idx >> 8;                         // 0..1295
  const int b = row / 162, pr = row - b * 162;
  unsigned short* o = xb + (size_t)row * 2048 + c;
  if (pr == 0 || pr == 161) {
    *(uint4*)o = make_uint4(0u, 0u, 0u, 0u);
  } else {
    const float* src = x + ((size_t)(b * 160 + pr - 1)) * 2048 + c;
    float4 v0 = *(const float4*)src;
    float4 v1 = *(const float4*)(src + 4);
    unsigned short r[8] = {f2bf(v0.x), f2bf(v0.y), f2bf(v0.z), f2bf(v0.w),
                           f2bf(v1.x), f2bf(v1.y), f2bf(v1.z), f2bf(v1.w)};
    *(uint4*)o = *(const uint4*)r;
  }
}

// ---------- cast w1 -> bf16, layout wb[tap][h][f] ----------
__global__ __launch_bounds__(256) void k_cvt_w(const float* __restrict__ w1,
                                               unsigned short* __restrict__ wb) {
  const int idx = blockIdx.x * 256 + threadIdx.x;   // 1536*256
  const int c = (idx & 255) * 8;
  const int rest = idx >> 8;                        // 0..1535
  const int h = rest & 511, tap = rest >> 9;
  const float* src = w1 + (size_t)h * (FEATD * 3) + (size_t)c * 3 + tap;
  unsigned short r[8];
  #pragma unroll
  for (int i = 0; i < 8; ++i) r[i] = f2bf(src[i * 3]);
  *(uint4*)&wb[((size_t)tap * HID + h) * FEATD + c] = *(const uint4*)r;
}

// ---------- conv1d as bf16 MFMA GEMM, K-split 4 ----------
// grid (20 m-tiles, 8 n-tiles, 4 kz), block 256 (4 waves, 2x2 of 16x16 frags each)
__global__ __launch_bounds__(256) void k_conv_mfma(const unsigned short* __restrict__ xb,
                                                   const unsigned short* __restrict__ wb,
                                                   float* __restrict__ part) {
  const int mt = blockIdx.x;
  const int h0 = blockIdx.y * 64;
  const int kz = blockIdx.z;
  const int tid = threadIdx.x;

  __shared__ short Alds[64 * 40];   // [row m][k 0..31], pad to 40
  __shared__ short Blds[64 * 40];   // [row n][k 0..31], pad to 40

  // staging: thread -> (row, 16B chunk)
  const int sr = tid >> 2;
  const int sc = (tid & 3) * 8;
  const int rm = mt * 64 + sr;
  const int b = rm / 160;
  const int t = rm - b * 160;
  const unsigned short* abase = xb + ((size_t)(b * 162 + t)) * FEATD + kz * 512 + sc;
  const unsigned short* bbase = wb + ((size_t)(h0 + sr)) * FEATD + kz * 512 + sc;

  const int wid = tid >> 6, lane = tid & 63;
  const int wr = wid >> 1, wc = wid & 1;
  const int fa0 = (wr * 32 + (lane & 15)) * 40 + (lane >> 4) * 8;
  const int fb0 = (wc * 32 + (lane & 15)) * 40 + (lane >> 4) * 8;

  f32x4 acc00 = {}, acc01 = {}, acc10 = {}, acc11 = {};

  for (int tap = 0; tap < 3; ++tap) {
    const unsigned short* ap = abase + (size_t)tap * FEATD;
    const unsigned short* bp = bbase + (size_t)tap * HID * FEATD;
    for (int kk = 0; kk < 16; ++kk) {
      *(uint4*)&Alds[sr * 40 + sc] = *(const uint4*)(ap + kk * 32);
      *(uint4*)&Blds[sr * 40 + sc] = *(const uint4*)(bp + kk * 32);
      __syncthreads();
      bfrag a0 = *(const bfrag*)&Alds[fa0];
      bfrag a1 = *(const bfrag*)&Alds[fa0 + 16 * 40];
      bfrag b0 = *(const bfrag*)&Blds[fb0];
      bfrag b1 = *(const bfrag*)&Blds[fb0 + 16 * 40];
      acc00 = __builtin_amdgcn_mfma_f32_16x16x32_bf16(a0, b0, acc00, 0, 0, 0);
      acc01 = __builtin_amdgcn_mfma_f32_16x16x32_bf16(a0, b1, acc01, 0, 0, 0);
      acc10 = __builtin_amdgcn_mfma_f32_16x16x32_bf16(a1, b0, acc10, 0, 0, 0);
      acc11 = __builtin_amdgcn_mfma_f32_16x16x32_bf16(a1, b1, acc11, 0, 0, 0);
      __syncthreads();
    }
  }

  // epilogue: C/D layout col=lane&15, row=(lane>>4)*4+reg  [m89]
  float* pout = part + (size_t)kz * (NB * TS) * HID;
  const int r0 = mt * 64 + wr * 32 + (lane >> 4) * 4;
  const int c0 = h0 + wc * 32 + (lane & 15);
  #pragma unroll
  for (int i = 0; i < 4; ++i) {
    pout[(size_t)(r0 + i) * HID + c0]            = acc00[i];
    pout[(size_t)(r0 + i) * HID + c0 + 16]       = acc01[i];
    pout[(size_t)(r0 + 16 + i) * HID + c0]       = acc10[i];
    pout[(size_t)(r0 + 16 + i) * HID + c0 + 16]  = acc11[i];
  }
}

// ---------- sum K-split partials + bias + relu ----------
__global__ __launch_bounds__(256) void k_bias_relu(const float* __restrict__ part,
                                                   const float* __restrict__ bias,
                                                   float* __restrict__ feat) {
  const int idx = blockIdx.x * 256 + threadIdx.x;   // < 163840 float4s
  const float4* p = (const float4*)part;
  float4 v0 = p[idx];
  float4 v1 = p[163840 + idx];
  float4 v2 = p[2 * 163840 + idx];
  float4 v3 = p[3 * 163840 + idx];
  const float4 bb = ((const float4*)bias)[idx & 127];
  float4 o;
  o.x = fmaxf(v0.x + v1.x + v2.x + v3.x + bb.x, 0.f);
  o.y = fmaxf(v0.y + v1.y + v2.y + v3.y + bb.y, 0.f);
  o.z = fmaxf(v0.z + v1.z + v2.z + v3.z + bb.z, 0.f);
  o.w = fmaxf(v0.w + v1.w + v2.w + v3.w + bb.w, 0.f);
  ((float4*)feat)[idx] = o;
}

// ---------- y_class (1x1 conv) + y_atn (k=3 conv + bias) ----------
__global__ __launch_bounds__(256) void k_head(const float* __restrict__ feat,
                                              const float* __restrict__ wc,
                                              const float* __restrict__ wa,
                                              const float* __restrict__ ba,
                                              float* __restrict__ y_class,
                                              float* __restrict__ y_atn) {
  __shared__ float wcs[NC * HID];
  __shared__ float was[HID * 3];
  const int tid = threadIdx.x;
  for (int e = tid; e < NC * HID; e += 256) wcs[e] = wc[e];
  for (int e = tid; e < HID * 3; e += 256) was[e] = wa[e];
  __syncthreads();
  const int wave = blockIdx.x * 4 + (tid >> 6);
  const int lane = tid & 63;
  const int b = wave / TS, t = wave - b * TS;
  const float* frow = &feat[((size_t)b * TS + t) * HID];
  float fc[8], fm[8], fp[8];
  #pragma unroll
  for (int i2 = 0; i2 < 8; ++i2) {
    int h = lane + 64 * i2;
    fc[i2] = frow[h];
    fm[i2] = (t > 0)      ? frow[h - HID] : 0.f;
    fp[i2] = (t < TS - 1) ? frow[h + HID] : 0.f;
  }
  #pragma unroll 4
  for (int c = 0; c < NC; ++c) {
    float p = 0.f;
    #pragma unroll
    for (int i2 = 0; i2 < 8; ++i2) p += fc[i2] * wcs[c * HID + lane + 64 * i2];
    #pragma unroll
    for (int off = 32; off; off >>= 1) p += __shfl_xor(p, off);
    if (lane == 0) y_class[((size_t)b * NC + c) * TS + t] = p;
  }
  float p = 0.f;
  #pragma unroll
  for (int i2 = 0; i2 < 8; ++i2) {
    int h = lane + 64 * i2;
    p += fm[i2] * was[h * 3 + 0] + fc[i2] * was[h * 3 + 1] + fp[i2] * was[h * 3 + 2];
  }
  #pragma unroll
  for (int off = 32; off; off >>= 1) p += __shfl_xor(p, off);
  if (lane == 0) y_atn[b * TS + t] = p + ba[0];
}

// ---------- attention pooling x_fg + y_fg ----------
__global__ __launch_bounds__(256) void k_fg(const float* __restrict__ feat,
                                            const float* __restrict__ y_atn,
                                            const float* __restrict__ wc,
                                            float* __restrict__ y_fg) {
  const int b = blockIdx.x;
  const int tid = threadIdx.x;
  __shared__ float sig[TS];
  __shared__ float red[4];
  __shared__ float xfg[HID];
  float s = 0.f;
  if (tid < TS) { s = 1.f / (1.f + expf(-y_atn[b * TS + tid])); sig[tid] = s; }
  float r = s;
  #pragma unroll
  for (int off = 32; off; off >>= 1) r += __shfl_xor(r, off);
  if ((tid & 63) == 0) red[tid >> 6] = r;
  __syncthreads();
  const float inv = 1.f / (red[0] + red[1] + red[2] + red[3] + 1e-8f);
  for (int h = tid; h < HID; h += 256) {
    float a = 0.f;
    for (int t = 0; t < TS; ++t) a += sig[t] * feat[((size_t)b * TS + t) * HID + h];
    xfg[h] = a * inv;
  }
  __syncthreads();
  const int wv = tid >> 6, lane = tid & 63;
  for (int c = wv; c < NC; c += 4) {
    float p = 0.f;
    #pragma unroll
    for (int i2 = 0; i2 < 8; ++i2) {
      int h = lane + 64 * i2;
      p += wc[c * HID + h] * xfg[h];
    }
    #pragma unroll
    for (int off = 32; off; off >>= 1) p += __shfl_xor(p, off);
    if (lane == 0) y_fg[b * NC + c] = p;
  }
}

// ---------- boundary-matching via analytic sparse mask ----------
__global__ __launch_bounds__(256) void k_bmn(const float* __restrict__ y_class,
                                             float* __restrict__ bmn) {
  const int b = blockIdx.x / 100;
  const int blk = blockIdx.x - b * 100;
  const int tid = threadIdx.x;
  __shared__ float Y[TS * 24];          // [t][c], padded to 24
  for (int e = tid; e < NC * TS; e += 256) {
    int c = e / TS, t = e - c * TS;
    Y[t * 24 + c] = y_class[((size_t)b * NC + c) * TS + t];
  }
  __syncthreads();
  const int idx = blk * 256 + tid;      // 0..25599
  const int i = idx / TS, j = idx - i * TS;
  float* ob = bmn + (size_t)b * 60 * TS * TS + (size_t)i * TS + j;
  const size_t cs = (size_t)TS * TS;
  if (j < i) {
    #pragma unroll 4
    for (int gc = 0; gc < 60; ++gc) ob[(size_t)gc * cs] = 0.f;
    return;
  }
  float ac[NC];
  auto step = [&](int k) {
    float pos = (float)(k * (j - i)) / 31.0f + (float)i;
    int dn = (int)pos;
    float frx = pos - (float)dn;
    int up = dn + (frx > 0.f ? 1 : 0);
    float wd = 1.f - frx;
    const float* yd = &Y[dn * 24];
    const float* yu = &Y[up * 24];
    #pragma unroll
    for (int c4 = 0; c4 < 5; ++c4) {
      float4 d4 = *(const float4*)(yd + c4 * 4);
      float4 u4 = *(const float4*)(yu + c4 * 4);
      ac[c4 * 4 + 0] += wd * d4.x + frx * u4.x;
      ac[c4 * 4 + 1] += wd * d4.y + frx * u4.y;
      ac[c4 * 4 + 2] += wd * d4.z + frx * u4.z;
      ac[c4 * 4 + 3] += wd * d4.w + frx * u4.w;
    }
  };
  #pragma unroll
  for (int c = 0; c < NC; ++c) ac[c] = 0.f;
  #pragma unroll 2
  for (int k = 0; k < 8; ++k) step(k);
  #pragma unroll
  for (int c = 0; c < NC; ++c) ob[(size_t)c * cs] = ac[c] * 0.125f;
  #pragma unroll
  for (int c = 0; c < NC; ++c) ac[c] = 0.f;
  #pragma unroll 2
  for (int k = 8; k < 24; ++k) step(k);
  #pragma unroll
  for (int c = 0; c < NC; ++c) ob[(size_t)(NC + c) * cs] = ac[c] * 0.0625f;
  #pragma unroll
  for (int c = 0; c < NC; ++c) ac[c] = 0.f;
  #pragma unroll 2
  for (int k = 24; k < 32; ++k) step(k);
  #pragma unroll
  for (int c = 0; c < NC; ++c) ob[(size_t)(2 * NC + c) * cs] = ac[c] * 0.125f;
}

extern "C" void kernel_launch(void* const* d_in, const int* in_sizes, int n_in,
                              void* d_out, int out_size, void* d_ws, size_t ws_size,
                              hipStream_t stream) {
  const float* x  = (const float*)d_in[0];
  // d_in[1] = sample_mask: unused (recomputed analytically)
  const float* w1 = (const float*)d_in[2];
  const float* b1 = (const float*)d_in[3];
  const float* wc = (const float*)d_in[4];
  const float* wa = (const float*)d_in[5];
  const float* ba = (const float*)d_in[6];

  float* out     = (float*)d_out;
  float* y_class = out;                            // [8,20,160]
  float* y_fg    = out + NB * NC * TS;             // [8,20,1]
  float* bmn     = out + NB * NC * TS + NB * NC;   // [8,60,160,160]

  float* part  = (float*)d_ws;                     // 4*1280*512 f32
  float* feat  = part + 4 * NB * TS * HID;         // 1280*512 f32
  float* y_atn = feat + NB * TS * HID;             // 1280 f32
  unsigned short* xb = (unsigned short*)(y_atn + 2048);   // 8*162*2048 bf16
  unsigned short* wb = xb + (size_t)NB * 162 * FEATD;     // 3*512*2048 bf16

  k_cvt_x<<<1296, 256, 0, stream>>>(x, xb);
  k_cvt_w<<<1536, 256, 0, stream>>>(w1, wb);
  k_conv_mfma<<<dim3(20, 8, 4), 256, 0, stream>>>(xb, wb, part);
  k_bias_relu<<<640, 256, 0, stream>>>(part, b1, feat);
  k_head<<<320, 256, 0, stream>>>(feat, wc, wa, ba, y_class, y_atn);
  k_fg<<<8, 256, 0, stream>>>(feat, y_atn, wc, y_fg);
  k_bmn<<<800, 256, 0, stream>>>(y_class, bmn);
}

// Round 3
// 85.848 us; speedup vs baseline: 2.5792x; 1.1772x over previous
//
#include <hip/hip_runtime.h>
#include <math.h>

#define TS 160
#define FEATD 2048
#define HID 512
#define NC 20
#define NB 8

typedef __attribute__((ext_vector_type(8))) short bfrag;
typedef __attribute__((ext_vector_type(4))) float f32x4;

static __device__ __forceinline__ unsigned short f2bf(float f) {
  unsigned int u = __float_as_uint(f);
  unsigned int r = (u + 0x7FFFu + ((u >> 16) & 1u)) >> 16;
  return (unsigned short)r;
}

static __device__ __forceinline__ void gload16(const void* g, void* l) {
  __builtin_amdgcn_global_load_lds((const __attribute__((address_space(1))) void*)g,
                                   (__attribute__((address_space(3))) void*)l, 16, 0, 0);
}

// ---------- fused cast: x -> xb (padded bf16) and w1 -> wb[tap][h][f] bf16 ----------
__global__ __launch_bounds__(256) void k_cvt(const float* __restrict__ x,
                                             const float* __restrict__ w1,
                                             unsigned short* __restrict__ xb,
                                             unsigned short* __restrict__ wb) {
  __shared__ float Ls[FEATD * 3];
  const int tid = threadIdx.x;
  if (blockIdx.x < 1296) {
    // x path: row = b*162 + pr; pr 0 and 161 are zero pads
    const int idx = blockIdx.x * 256 + tid;
    const int c = (idx & 255) * 8;
    const int row = idx >> 8;
    const int b = row / 162, pr = row - b * 162;
    unsigned short* o = xb + (size_t)row * FEATD + c;
    if (pr == 0 || pr == 161) {
      *(uint4*)o = make_uint4(0u, 0u, 0u, 0u);
    } else {
      const float* src = x + ((size_t)(b * TS + pr - 1)) * FEATD + c;
      float4 v0 = *(const float4*)src;
      float4 v1 = *(const float4*)(src + 4);
      unsigned short r[8] = {f2bf(v0.x), f2bf(v0.y), f2bf(v0.z), f2bf(v0.w),
                             f2bf(v1.x), f2bf(v1.y), f2bf(v1.z), f2bf(v1.w)};
      *(uint4*)o = *(const uint4*)r;
    }
  } else {
    // w path: one h row per block, LDS-staged coalesced transpose
    const int h = blockIdx.x - 1296;
    const float4* src = (const float4*)(w1 + (size_t)h * (FEATD * 3));
    for (int e = tid; e < FEATD * 3 / 4; e += 256) ((float4*)Ls)[e] = src[e];
    __syncthreads();
    for (int oc = tid; oc < 768; oc += 256) {
      const int tap = oc >> 8;
      const int f0 = (oc & 255) * 8;
      unsigned short r[8];
      #pragma unroll
      for (int i = 0; i < 8; ++i) r[i] = f2bf(Ls[(f0 + i) * 3 + tap]);
      *(uint4*)&wb[((size_t)tap * HID + h) * FEATD + f0] = *(const uint4*)r;
    }
  }
}

// ---------- conv1d as bf16 MFMA GEMM: tap-shared staging, global_load_lds, swizzled ----------
// grid (8 b, 8 n, 8 kz), block 256 (4 waves 2x2), wave tile 80x32, BK=64 per stage
__global__ __launch_bounds__(256, 2) void k_conv_mfma(const unsigned short* __restrict__ xb,
                                                      const unsigned short* __restrict__ wb,
                                                      float* __restrict__ part) {
  const int bb = blockIdx.x;
  const int h0 = blockIdx.y * 64;
  const int kz = blockIdx.z;
  const int tid = threadIdx.x;
  const int wid = tid >> 6, lane = tid & 63;

  __shared__ unsigned short Alds[162 * 64];     // [pr][64 f] bf16, chunk-swizzled
  __shared__ unsigned short Blds[3 * 64 * 64];  // [tap][h][64 f] bf16, chunk-swizzled

  const unsigned short* xbb = xb + (size_t)bb * 162 * FEATD;
  const unsigned short* wbb = wb + (size_t)h0 * FEATD;

  f32x4 acc[5][2] = {};
  const int wr = wid >> 1, wc = wid & 1;

  for (int s = 0; s < 4; ++s) {
    const int f0 = kz * 256 + s * 64;
    // A rows 0..159 : 5 full gload_lds issues (content[row][c] = global chunk c^(row&7))
    #pragma unroll
    for (int is = 0; is < 5; ++is) {
      const int ci = is * 256 + wid * 64 + lane;
      const int row = ci >> 3, c = ci & 7;
      gload16(xbb + (size_t)row * FEATD + f0 + ((c ^ (row & 7)) << 3),
              (char*)Alds + (size_t)(is * 256 + wid * 64) * 16);
    }
    // B: 3 taps x 64 rows x 8 chunks = 6 full issues
    #pragma unroll
    for (int is = 0; is < 6; ++is) {
      const int ci = is * 256 + wid * 64 + lane;
      const int tap = ci >> 9, rr = (ci >> 3) & 63, c = ci & 7;
      gload16(wbb + (size_t)tap * (HID * FEATD) + (size_t)rr * FEATD + f0 + ((c ^ (rr & 7)) << 3),
              (char*)Blds + (size_t)(is * 256 + wid * 64) * 16);
    }
    // A tail rows 160,161 via plain load + ds_write (same swizzle)
    if (tid < 16) {
      const int row = 160 + (tid >> 3), c = tid & 7;
      uint4 v = *(const uint4*)(xbb + (size_t)row * FEATD + f0 + ((c ^ (row & 7)) << 3));
      *(uint4*)((char*)Alds + row * 128 + c * 16) = v;
    }
    __syncthreads();

    #pragma unroll
    for (int tap = 0; tap < 3; ++tap) {
      #pragma unroll
      for (int kk = 0; kk < 2; ++kk) {
        const int cread = kk * 4 + (lane >> 4);
        bfrag bf0, bf1;
        {
          const int hh0 = wc * 32 + (lane & 15);
          const int hh1 = hh0 + 16;
          bf0 = *(const bfrag*)((char*)Blds + tap * 8192 + hh0 * 128 + ((cread ^ (hh0 & 7)) << 4));
          bf1 = *(const bfrag*)((char*)Blds + tap * 8192 + hh1 * 128 + ((cread ^ (hh1 & 7)) << 4));
        }
        #pragma unroll
        for (int mi = 0; mi < 5; ++mi) {
          const int rr = wr * 80 + mi * 16 + (lane & 15) + tap;
          bfrag af = *(const bfrag*)((char*)Alds + rr * 128 + ((cread ^ (rr & 7)) << 4));
          acc[mi][0] = __builtin_amdgcn_mfma_f32_16x16x32_bf16(af, bf0, acc[mi][0], 0, 0, 0);
          acc[mi][1] = __builtin_amdgcn_mfma_f32_16x16x32_bf16(af, bf1, acc[mi][1], 0, 0, 0);
        }
      }
    }
    __syncthreads();
  }

  // epilogue: C/D layout col=lane&15, row=(lane>>4)*4+reg
  float* pout = part + (size_t)kz * (NB * TS) * HID;
  #pragma unroll
  for (int mi = 0; mi < 5; ++mi) {
    const int r0 = bb * TS + wr * 80 + mi * 16 + (lane >> 4) * 4;
    #pragma unroll
    for (int ni = 0; ni < 2; ++ni) {
      const int c0 = h0 + wc * 32 + ni * 16 + (lane & 15);
      #pragma unroll
      for (int i = 0; i < 4; ++i)
        pout[(size_t)(r0 + i) * HID + c0] = acc[mi][ni][i];
    }
  }
}

// ---------- sum 8 K-split partials + bias + relu ----------
__global__ __launch_bounds__(256) void k_bias_relu(const float* __restrict__ part,
                                                   const float* __restrict__ bias,
                                                   float* __restrict__ feat) {
  const int idx = blockIdx.x * 256 + threadIdx.x;   // < 163840 float4s
  const float4* p = (const float4*)part;
  float4 a = p[idx];
  #pragma unroll
  for (int k = 1; k < 8; ++k) {
    float4 v = p[(size_t)k * 163840 + idx];
    a.x += v.x; a.y += v.y; a.z += v.z; a.w += v.w;
  }
  const float4 bb = ((const float4*)bias)[idx & 127];
  float4 o;
  o.x = fmaxf(a.x + bb.x, 0.f);
  o.y = fmaxf(a.y + bb.y, 0.f);
  o.z = fmaxf(a.z + bb.z, 0.f);
  o.w = fmaxf(a.w + bb.w, 0.f);
  ((float4*)feat)[idx] = o;
}

// ---------- y_class (1x1 conv) + y_atn (k=3 conv + bias) ----------
__global__ __launch_bounds__(256) void k_head(const float* __restrict__ feat,
                                              const float* __restrict__ wc,
                                              const float* __restrict__ wa,
                                              const float* __restrict__ ba,
                                              float* __restrict__ y_class,
                                              float* __restrict__ y_atn) {
  __shared__ float wcs[NC * HID];
  __shared__ float was[HID * 3];
  const int tid = threadIdx.x;
  for (int e = tid; e < NC * HID; e += 256) wcs[e] = wc[e];
  for (int e = tid; e < HID * 3; e += 256) was[e] = wa[e];
  __syncthreads();
  const int wave = blockIdx.x * 4 + (tid >> 6);
  const int lane = tid & 63;
  const int b = wave / TS, t = wave - b * TS;
  const float* frow = &feat[((size_t)b * TS + t) * HID];
  float fc[8], fm[8], fp[8];
  #pragma unroll
  for (int i2 = 0; i2 < 8; ++i2) {
    int h = lane + 64 * i2;
    fc[i2] = frow[h];
    fm[i2] = (t > 0)      ? frow[h - HID] : 0.f;
    fp[i2] = (t < TS - 1) ? frow[h + HID] : 0.f;
  }
  #pragma unroll 4
  for (int c = 0; c < NC; ++c) {
    float p = 0.f;
    #pragma unroll
    for (int i2 = 0; i2 < 8; ++i2) p += fc[i2] * wcs[c * HID + lane + 64 * i2];
    #pragma unroll
    for (int off = 32; off; off >>= 1) p += __shfl_xor(p, off);
    if (lane == 0) y_class[((size_t)b * NC + c) * TS + t] = p;
  }
  float p = 0.f;
  #pragma unroll
  for (int i2 = 0; i2 < 8; ++i2) {
    int h = lane + 64 * i2;
    p += fm[i2] * was[h * 3 + 0] + fc[i2] * was[h * 3 + 1] + fp[i2] * was[h * 3 + 2];
  }
  #pragma unroll
  for (int off = 32; off; off >>= 1) p += __shfl_xor(p, off);
  if (lane == 0) y_atn[b * TS + t] = p + ba[0];
}

// ---------- attention pooling x_fg + y_fg ----------
__global__ __launch_bounds__(256) void k_fg(const float* __restrict__ feat,
                                            const float* __restrict__ y_atn,
                                            const float* __restrict__ wc,
                                            float* __restrict__ y_fg) {
  const int b = blockIdx.x;
  const int tid = threadIdx.x;
  __shared__ float sig[TS];
  __shared__ float red[4];
  __shared__ float xfg[HID];
  float s = 0.f;
  if (tid < TS) { s = 1.f / (1.f + expf(-y_atn[b * TS + tid])); sig[tid] = s; }
  float r = s;
  #pragma unroll
  for (int off = 32; off; off >>= 1) r += __shfl_xor(r, off);
  if ((tid & 63) == 0) red[tid >> 6] = r;
  __syncthreads();
  const float inv = 1.f / (red[0] + red[1] + red[2] + red[3] + 1e-8f);
  for (int h = tid; h < HID; h += 256) {
    float a = 0.f;
    for (int t = 0; t < TS; ++t) a += sig[t] * feat[((size_t)b * TS + t) * HID + h];
    xfg[h] = a * inv;
  }
  __syncthreads();
  const int wv = tid >> 6, lane = tid & 63;
  for (int c = wv; c < NC; c += 4) {
    float p = 0.f;
    #pragma unroll
    for (int i2 = 0; i2 < 8; ++i2) {
      int h = lane + 64 * i2;
      p += wc[c * HID + h] * xfg[h];
    }
    #pragma unroll
    for (int off = 32; off; off >>= 1) p += __shfl_xor(p, off);
    if (lane == 0) y_fg[b * NC + c] = p;
  }
}

// ---------- boundary-matching via analytic sparse mask (swizzled Y rows) ----------
__global__ __launch_bounds__(256) void k_bmn(const float* __restrict__ y_class,
                                             float* __restrict__ bmn) {
  const int b = blockIdx.x / 100;
  const int blk = blockIdx.x - b * 100;
  const int tid = threadIdx.x;
  __shared__ float Ys[TS * 32];         // [t][8 chunks of 4 floats], chunk-swizzled
  for (int e = tid; e < NC * TS; e += 256) {
    int c = e / TS, t = e - c * TS;
    Ys[t * 32 + (((c >> 2) ^ (t & 7)) << 2) + (c & 3)] = y_class[((size_t)b * NC + c) * TS + t];
  }
  __syncthreads();
  const int idx = blk * 256 + tid;      // 0..25599
  const int i = idx / TS, j = idx - i * TS;
  float* ob = bmn + (size_t)b * 60 * TS * TS + (size_t)i * TS + j;
  const size_t cs = (size_t)TS * TS;
  if (j < i) {
    #pragma unroll 4
    for (int gc = 0; gc < 60; ++gc) ob[(size_t)gc * cs] = 0.f;
    return;
  }
  float ac[NC];
  auto step = [&](int k) {
    float pos = (float)(k * (j - i)) / 31.0f + (float)i;
    int dn = (int)pos;
    float frx = pos - (float)dn;
    int up = dn + (frx > 0.f ? 1 : 0);
    float wd = 1.f - frx;
    const float* yd = &Ys[dn * 32];
    const float* yu = &Ys[up * 32];
    #pragma unroll
    for (int c4 = 0; c4 < 5; ++c4) {
      float4 d4 = *(const float4*)(yd + ((c4 ^ (dn & 7)) << 2));
      float4 u4 = *(const float4*)(yu + ((c4 ^ (up & 7)) << 2));
      ac[c4 * 4 + 0] += wd * d4.x + frx * u4.x;
      ac[c4 * 4 + 1] += wd * d4.y + frx * u4.y;
      ac[c4 * 4 + 2] += wd * d4.z + frx * u4.z;
      ac[c4 * 4 + 3] += wd * d4.w + frx * u4.w;
    }
  };
  #pragma unroll
  for (int c = 0; c < NC; ++c) ac[c] = 0.f;
  #pragma unroll 2
  for (int k = 0; k < 8; ++k) step(k);
  #pragma unroll
  for (int c = 0; c < NC; ++c) ob[(size_t)c * cs] = ac[c] * 0.125f;
  #pragma unroll
  for (int c = 0; c < NC; ++c) ac[c] = 0.f;
  #pragma unroll 2
  for (int k = 8; k < 24; ++k) step(k);
  #pragma unroll
  for (int c = 0; c < NC; ++c) ob[(size_t)(NC + c) * cs] = ac[c] * 0.0625f;
  #pragma unroll
  for (int c = 0; c < NC; ++c) ac[c] = 0.f;
  #pragma unroll 2
  for (int k = 24; k < 32; ++k) step(k);
  #pragma unroll
  for (int c = 0; c < NC; ++c) ob[(size_t)(2 * NC + c) * cs] = ac[c] * 0.125f;
}

extern "C" void kernel_launch(void* const* d_in, const int* in_sizes, int n_in,
                              void* d_out, int out_size, void* d_ws, size_t ws_size,
                              hipStream_t stream) {
  const float* x  = (const float*)d_in[0];
  // d_in[1] = sample_mask: unused (recomputed analytically)
  const float* w1 = (const float*)d_in[2];
  const float* b1 = (const float*)d_in[3];
  const float* wc = (const float*)d_in[4];
  const float* wa = (const float*)d_in[5];
  const float* ba = (const float*)d_in[6];

  float* out     = (float*)d_out;
  float* y_class = out;                            // [8,20,160]
  float* y_fg    = out + NB * NC * TS;             // [8,20,1]
  float* bmn     = out + NB * NC * TS + NB * NC;   // [8,60,160,160]

  float* part  = (float*)d_ws;                     // 8*1280*512 f32
  float* feat  = part + 8 * NB * TS * HID;         // 1280*512 f32
  float* y_atn = feat + NB * TS * HID;             // 1280 f32 (pad to 2048)
  unsigned short* xb = (unsigned short*)(y_atn + 2048);   // 8*162*2048 bf16
  unsigned short* wb = xb + (size_t)NB * 162 * FEATD;     // 3*512*2048 bf16

  k_cvt<<<1296 + 512, 256, 0, stream>>>(x, w1, xb, wb);
  k_conv_mfma<<<dim3(8, 8, 8), 256, 0, stream>>>(xb, wb, part);
  k_bias_relu<<<640, 256, 0, stream>>>(part, b1, feat);
  k_head<<<320, 256, 0, stream>>>(feat, wc, wa, ba, y_class, y_atn);
  k_fg<<<8, 256, 0, stream>>>(feat, y_atn, wc, y_fg);
  k_bmn<<<800, 256, 0, stream>>>(y_class, bmn);
}

// Round 4
// 80.730 us; speedup vs baseline: 2.7427x; 1.0634x over previous
//
#include <hip/hip_runtime.h>
#include <math.h>

#define TS 160
#define FEATD 2048
#define HID 512
#define NC 20
#define NB 8

typedef __attribute__((ext_vector_type(8))) short bfrag;
typedef __attribute__((ext_vector_type(4))) float f32x4;

static __device__ __forceinline__ unsigned short f2bf(float f) {
  unsigned int u = __float_as_uint(f);
  unsigned int r = (u + 0x7FFFu + ((u >> 16) & 1u)) >> 16;
  return (unsigned short)r;
}

static __device__ __forceinline__ void gload16(const void* g, void* l) {
  __builtin_amdgcn_global_load_lds((const __attribute__((address_space(1))) void*)g,
                                   (__attribute__((address_space(3))) void*)l, 16, 0, 0);
}

// ---------- fused cast: x -> xb (padded bf16) and w1 -> wb[tap][h][f] bf16 ----------
__global__ __launch_bounds__(256) void k_cvt(const float* __restrict__ x,
                                             const float* __restrict__ w1,
                                             unsigned short* __restrict__ xb,
                                             unsigned short* __restrict__ wb) {
  __shared__ float Ls[FEATD * 3];
  const int tid = threadIdx.x;
  if (blockIdx.x < 1296) {
    const int idx = blockIdx.x * 256 + tid;
    const int c = (idx & 255) * 8;
    const int row = idx >> 8;
    const int b = row / 162, pr = row - b * 162;
    unsigned short* o = xb + (size_t)row * FEATD + c;
    if (pr == 0 || pr == 161) {
      *(uint4*)o = make_uint4(0u, 0u, 0u, 0u);
    } else {
      const float* src = x + ((size_t)(b * TS + pr - 1)) * FEATD + c;
      float4 v0 = *(const float4*)src;
      float4 v1 = *(const float4*)(src + 4);
      unsigned short r[8] = {f2bf(v0.x), f2bf(v0.y), f2bf(v0.z), f2bf(v0.w),
                             f2bf(v1.x), f2bf(v1.y), f2bf(v1.z), f2bf(v1.w)};
      *(uint4*)o = *(const uint4*)r;
    }
  } else {
    const int h = blockIdx.x - 1296;
    const float4* src = (const float4*)(w1 + (size_t)h * (FEATD * 3));
    for (int e = tid; e < FEATD * 3 / 4; e += 256) ((float4*)Ls)[e] = src[e];
    __syncthreads();
    for (int oc = tid; oc < 768; oc += 256) {
      const int tap = oc >> 8;
      const int f0 = (oc & 255) * 8;
      unsigned short r[8];
      #pragma unroll
      for (int i = 0; i < 8; ++i) r[i] = f2bf(Ls[(f0 + i) * 3 + tap]);
      *(uint4*)&wb[((size_t)tap * HID + h) * FEATD + f0] = *(const uint4*)r;
    }
  }
}

// ---------- W interpolation table: WT[g][d+160][tau] bf16, rows d<0 are zero ----------
__global__ __launch_bounds__(256) void k_wbuild(unsigned short* __restrict__ WT) {
  const int idx = blockIdx.x * 256 + threadIdx.x;   // 600*256 = 153600
  const int tau = idx % 160;
  const int dd = (idx / 160) % 320;
  const int g = idx / (160 * 320);
  float w = 0.f;
  if (dd >= 160) {
    const int d = dd - 160;
    const int k0 = (g == 0) ? 0 : (g == 1 ? 8 : 24);
    const int k1 = (g == 0) ? 8 : (g == 1 ? 24 : 32);
    for (int k = k0; k < k1; ++k) {
      float p = (float)(d * k) / 31.0f;
      float a = fabsf(p - (float)tau);
      w += fmaxf(0.f, 1.f - a);
    }
    w *= (g == 1) ? 0.0625f : 0.125f;
  }
  WT[idx] = f2bf(w);
}

// ---------- conv1d as bf16 MFMA GEMM: tap-shared staging ----------
__global__ __launch_bounds__(256, 3) void k_conv_mfma(const unsigned short* __restrict__ xb,
                                                      const unsigned short* __restrict__ wb,
                                                      float* __restrict__ part) {
  const int bb = blockIdx.x;
  const int h0 = blockIdx.y * 64;
  const int kz = blockIdx.z;
  const int tid = threadIdx.x;
  const int wid = tid >> 6, lane = tid & 63;

  __shared__ unsigned short Alds[162 * 64];
  __shared__ unsigned short Blds[3 * 64 * 64];

  const unsigned short* xbb = xb + (size_t)bb * 162 * FEATD;
  const unsigned short* wbb = wb + (size_t)h0 * FEATD;

  f32x4 acc[5][2] = {};
  const int wr = wid >> 1, wc = wid & 1;

  for (int s = 0; s < 4; ++s) {
    const int f0 = kz * 256 + s * 64;
    #pragma unroll
    for (int is = 0; is < 5; ++is) {
      const int ci = is * 256 + wid * 64 + lane;
      const int row = ci >> 3, c = ci & 7;
      gload16(xbb + (size_t)row * FEATD + f0 + ((c ^ (row & 7)) << 3),
              (char*)Alds + (size_t)(is * 256 + wid * 64) * 16);
    }
    #pragma unroll
    for (int is = 0; is < 6; ++is) {
      const int ci = is * 256 + wid * 64 + lane;
      const int tap = ci >> 9, rr = (ci >> 3) & 63, c = ci & 7;
      gload16(wbb + (size_t)tap * (HID * FEATD) + (size_t)rr * FEATD + f0 + ((c ^ (rr & 7)) << 3),
              (char*)Blds + (size_t)(is * 256 + wid * 64) * 16);
    }
    if (tid < 16) {
      const int row = 160 + (tid >> 3), c = tid & 7;
      uint4 v = *(const uint4*)(xbb + (size_t)row * FEATD + f0 + ((c ^ (row & 7)) << 3));
      *(uint4*)((char*)Alds + row * 128 + c * 16) = v;
    }
    __syncthreads();

    #pragma unroll
    for (int tap = 0; tap < 3; ++tap) {
      #pragma unroll
      for (int kk = 0; kk < 2; ++kk) {
        const int cread = kk * 4 + (lane >> 4);
        bfrag bf0, bf1;
        {
          const int hh0 = wc * 32 + (lane & 15);
          const int hh1 = hh0 + 16;
          bf0 = *(const bfrag*)((char*)Blds + tap * 8192 + hh0 * 128 + ((cread ^ (hh0 & 7)) << 4));
          bf1 = *(const bfrag*)((char*)Blds + tap * 8192 + hh1 * 128 + ((cread ^ (hh1 & 7)) << 4));
        }
        #pragma unroll
        for (int mi = 0; mi < 5; ++mi) {
          const int rr = wr * 80 + mi * 16 + (lane & 15) + tap;
          bfrag af = *(const bfrag*)((char*)Alds + rr * 128 + ((cread ^ (rr & 7)) << 4));
          acc[mi][0] = __builtin_amdgcn_mfma_f32_16x16x32_bf16(af, bf0, acc[mi][0], 0, 0, 0);
          acc[mi][1] = __builtin_amdgcn_mfma_f32_16x16x32_bf16(af, bf1, acc[mi][1], 0, 0, 0);
        }
      }
    }
    __syncthreads();
  }

  float* pout = part + (size_t)kz * (NB * TS) * HID;
  #pragma unroll
  for (int mi = 0; mi < 5; ++mi) {
    const int r0 = bb * TS + wr * 80 + mi * 16 + (lane >> 4) * 4;
    #pragma unroll
    for (int ni = 0; ni < 2; ++ni) {
      const int c0 = h0 + wc * 32 + ni * 16 + (lane & 15);
      #pragma unroll
      for (int i = 0; i < 4; ++i)
        pout[(size_t)(r0 + i) * HID + c0] = acc[mi][ni][i];
    }
  }
}

// ---------- sum 8 K-split partials + bias + relu ----------
__global__ __launch_bounds__(256) void k_bias_relu(const float* __restrict__ part,
                                                   const float* __restrict__ bias,
                                                   float* __restrict__ feat) {
  const int idx = blockIdx.x * 256 + threadIdx.x;
  const float4* p = (const float4*)part;
  float4 a = p[idx];
  #pragma unroll
  for (int k = 1; k < 8; ++k) {
    float4 v = p[(size_t)k * 163840 + idx];
    a.x += v.x; a.y += v.y; a.z += v.z; a.w += v.w;
  }
  const float4 bb = ((const float4*)bias)[idx & 127];
  float4 o;
  o.x = fmaxf(a.x + bb.x, 0.f);
  o.y = fmaxf(a.y + bb.y, 0.f);
  o.z = fmaxf(a.z + bb.z, 0.f);
  o.w = fmaxf(a.w + bb.w, 0.f);
  ((float4*)feat)[idx] = o;
}

// ---------- y_class + y_atn ----------
__global__ __launch_bounds__(256) void k_head(const float* __restrict__ feat,
                                              const float* __restrict__ wc,
                                              const float* __restrict__ wa,
                                              const float* __restrict__ ba,
                                              float* __restrict__ y_class,
                                              float* __restrict__ y_atn) {
  __shared__ float wcs[NC * HID];
  __shared__ float was[HID * 3];
  const int tid = threadIdx.x;
  for (int e = tid; e < NC * HID; e += 256) wcs[e] = wc[e];
  for (int e = tid; e < HID * 3; e += 256) was[e] = wa[e];
  __syncthreads();
  const int wave = blockIdx.x * 4 + (tid >> 6);
  const int lane = tid & 63;
  const int b = wave / TS, t = wave - b * TS;
  const float* frow = &feat[((size_t)b * TS + t) * HID];
  float fc[8], fm[8], fp[8];
  #pragma unroll
  for (int i2 = 0; i2 < 8; ++i2) {
    int h = lane + 64 * i2;
    fc[i2] = frow[h];
    fm[i2] = (t > 0)      ? frow[h - HID] : 0.f;
    fp[i2] = (t < TS - 1) ? frow[h + HID] : 0.f;
  }
  #pragma unroll 4
  for (int c = 0; c < NC; ++c) {
    float p = 0.f;
    #pragma unroll
    for (int i2 = 0; i2 < 8; ++i2) p += fc[i2] * wcs[c * HID + lane + 64 * i2];
    #pragma unroll
    for (int off = 32; off; off >>= 1) p += __shfl_xor(p, off);
    if (lane == 0) y_class[((size_t)b * NC + c) * TS + t] = p;
  }
  float p = 0.f;
  #pragma unroll
  for (int i2 = 0; i2 < 8; ++i2) {
    int h = lane + 64 * i2;
    p += fm[i2] * was[h * 3 + 0] + fc[i2] * was[h * 3 + 1] + fp[i2] * was[h * 3 + 2];
  }
  #pragma unroll
  for (int off = 32; off; off >>= 1) p += __shfl_xor(p, off);
  if (lane == 0) y_atn[b * TS + t] = p + ba[0];
}

// ---------- attention pooling ----------
__global__ __launch_bounds__(256) void k_fg(const float* __restrict__ feat,
                                            const float* __restrict__ y_atn,
                                            const float* __restrict__ wc,
                                            float* __restrict__ y_fg) {
  const int b = blockIdx.x;
  const int tid = threadIdx.x;
  __shared__ float sig[TS];
  __shared__ float red[4];
  __shared__ float xfg[HID];
  float s = 0.f;
  if (tid < TS) { s = 1.f / (1.f + expf(-y_atn[b * TS + tid])); sig[tid] = s; }
  float r = s;
  #pragma unroll
  for (int off = 32; off; off >>= 1) r += __shfl_xor(r, off);
  if ((tid & 63) == 0) red[tid >> 6] = r;
  __syncthreads();
  const float inv = 1.f / (red[0] + red[1] + red[2] + red[3] + 1e-8f);
  for (int h = tid; h < HID; h += 256) {
    float a = 0.f;
    for (int t = 0; t < TS; ++t) a += sig[t] * feat[((size_t)b * TS + t) * HID + h];
    xfg[h] = a * inv;
  }
  __syncthreads();
  const int wv = tid >> 6, lane = tid & 63;
  for (int c = wv; c < NC; c += 4) {
    float p = 0.f;
    #pragma unroll
    for (int i2 = 0; i2 < 8; ++i2) {
      int h = lane + 64 * i2;
      p += wc[c * HID + h] * xfg[h];
    }
    #pragma unroll
    for (int off = 32; off; off >>= 1) p += __shfl_xor(p, off);
    if (lane == 0) y_fg[b * NC + c] = p;
  }
}

// ---------- 8 shifted bf16 copies of y_class: Ys[s][bc][336], col tau = Y[bc][tau+s] ----------
__global__ __launch_bounds__(256) void k_ysbuild(const float* __restrict__ y_class,
                                                 unsigned short* __restrict__ Ys) {
  const int idx = blockIdx.x * 256 + threadIdx.x;   // 210*256 = 53760 = 8*160*42
  const int c8 = idx % 42;
  const int bc = (idx / 42) % 160;
  const int s = idx / (42 * 160);
  unsigned short r[8];
  #pragma unroll
  for (int e = 0; e < 8; ++e) {
    const int tpos = c8 * 8 + e + s;
    r[e] = (c8 * 8 + e < 336 && tpos < 160) ? f2bf(y_class[bc * 160 + tpos]) : (unsigned short)0;
  }
  *(uint4*)&Ys[((size_t)s * 160 + bc) * 336 + c8 * 8] = *(const uint4*)r;
}

// ---------- bmn as per-(i,g) 160x160x160 bf16 GEMM ----------
// A[bc][tau] = Y[bc][i+tau]  (shifted copy s = i&7, chunk-aligned)
// B'[tau][j] = W[g][tau][j-i] staged transposed: Wlds[j][tau] = WT[g][(j-i)+160][tau]
// LDS rows: 20 real chunks padded to 25 (odd stride -> free slot swizzle)
__global__ __launch_bounds__(256, 1) void k_bmn_mfma(const unsigned short* __restrict__ Ys,
                                                     const unsigned short* __restrict__ WT,
                                                     float* __restrict__ bmn) {
  const int i = blockIdx.x;
  const int g = blockIdx.y;
  const int tid = threadIdx.x;
  const int wid = tid >> 6, lane = tid & 63;

  __shared__ char Alds[65536];
  __shared__ char Wlds[65536];

  const int s = i & 7;
  const char* ysb = (const char*)(Ys + (size_t)s * 160 * 336) + (size_t)(i - s) * 2;
  const char* wtb = (const char*)(WT + (size_t)g * 320 * 160) + (size_t)(160 - i) * 320;

  // stage: 4096 chunk-loads each (rows clamped; pad chunks read row base)
  #pragma unroll
  for (int it = 0; it < 16; ++it) {
    const int idx = it * 256 + tid;
    int row = idx / 25, c = idx - row * 25;
    if (row > 159) row = 159;
    if (c > 19) c = 0;
    gload16(ysb + (size_t)row * 672 + c * 16, Alds + (size_t)idx * 16);
    gload16(wtb + (size_t)row * 320 + c * 16, Wlds + (size_t)idx * 16);
  }
  __syncthreads();

  const int wr = wid >> 1, wc = wid & 1;
  f32x4 acc[5][5] = {};

  #pragma unroll
  for (int ks = 0; ks < 5; ++ks) {
    const int cc = ks * 4 + (lane >> 4);
    bfrag bfr[5];
    #pragma unroll
    for (int nf = 0; nf < 5; ++nf) {
      const int j = wc * 80 + nf * 16 + (lane & 15);
      bfr[nf] = *(const bfrag*)(Wlds + (size_t)j * 400 + cc * 16);
    }
    #pragma unroll
    for (int mf = 0; mf < 5; ++mf) {
      const int r = wr * 80 + mf * 16 + (lane & 15);
      bfrag af = *(const bfrag*)(Alds + (size_t)r * 400 + cc * 16);
      #pragma unroll
      for (int nf = 0; nf < 5; ++nf)
        acc[mf][nf] = __builtin_amdgcn_mfma_f32_16x16x32_bf16(af, bfr[nf], acc[mf][nf], 0, 0, 0);
    }
  }

  // epilogue: row r -> (b = r/20, c = r%20), channel g*20+c; col j coalesced
  #pragma unroll
  for (int mf = 0; mf < 5; ++mf) {
    const int r0 = wr * 80 + mf * 16 + (lane >> 4) * 4;
    #pragma unroll
    for (int reg = 0; reg < 4; ++reg) {
      const int r = r0 + reg;
      const int b = r / 20, c = r - b * 20;
      float* base = bmn + (((size_t)(b * 60 + g * 20 + c) * TS) + i) * TS;
      #pragma unroll
      for (int nf = 0; nf < 5; ++nf) {
        const int j = wc * 80 + nf * 16 + (lane & 15);
        base[j] = acc[mf][nf][reg];
      }
    }
  }
}

extern "C" void kernel_launch(void* const* d_in, const int* in_sizes, int n_in,
                              void* d_out, int out_size, void* d_ws, size_t ws_size,
                              hipStream_t stream) {
  const float* x  = (const float*)d_in[0];
  const float* w1 = (const float*)d_in[2];
  const float* b1 = (const float*)d_in[3];
  const float* wc = (const float*)d_in[4];
  const float* wa = (const float*)d_in[5];
  const float* ba = (const float*)d_in[6];

  float* out     = (float*)d_out;
  float* y_class = out;                            // [8,20,160]
  float* y_fg    = out + NB * NC * TS;             // [8,20,1]
  float* bmn     = out + NB * NC * TS + NB * NC;   // [8,60,160,160]

  float* part  = (float*)d_ws;                     // 8*1280*512 f32
  float* feat  = part + 8 * NB * TS * HID;         // 1280*512 f32
  float* y_atn = feat + NB * TS * HID;             // 1280 f32 (pad 2048)
  unsigned short* xb = (unsigned short*)(y_atn + 2048);   // 8*162*2048 bf16
  unsigned short* wb = xb + (size_t)NB * 162 * FEATD;     // 3*512*2048 bf16
  unsigned short* WT = wb + (size_t)3 * HID * FEATD;      // 3*320*160 bf16
  unsigned short* Ys = WT + (size_t)3 * 320 * 160;        // 8*160*336 bf16

  k_wbuild<<<600, 256, 0, stream>>>(WT);
  k_cvt<<<1296 + 512, 256, 0, stream>>>(x, w1, xb, wb);
  k_conv_mfma<<<dim3(8, 8, 8), 256, 0, stream>>>(xb, wb, part);
  k_bias_relu<<<640, 256, 0, stream>>>(part, b1, feat);
  k_head<<<320, 256, 0, stream>>>(feat, wc, wa, ba, y_class, y_atn);
  k_fg<<<8, 256, 0, stream>>>(feat, y_atn, wc, y_fg);
  k_ysbuild<<<210, 256, 0, stream>>>(y_class, Ys);
  k_bmn_mfma<<<dim3(160, 3), 256, 0, stream>>>(Ys, WT, bmn);
}

// Round 5
// 76.078 us; speedup vs baseline: 2.9104x; 1.0611x over previous
//
#include <hip/hip_runtime.h>
#include <math.h>

#define TS 160
#define FEATD 2048
#define HID 512
#define NC 20
#define NB 8

typedef __attribute__((ext_vector_type(8))) short bfrag;
typedef __attribute__((ext_vector_type(4))) float f32x4;

static __device__ __forceinline__ unsigned short f2bf(float f) {
  unsigned int u = __float_as_uint(f);
  unsigned int r = (u + 0x7FFFu + ((u >> 16) & 1u)) >> 16;
  return (unsigned short)r;
}
static __device__ __forceinline__ float bf2f(unsigned short s) {
  return __uint_as_float(((unsigned int)s) << 16);
}

static __device__ __forceinline__ void gload16(const void* g, void* l) {
  __builtin_amdgcn_global_load_lds((const __attribute__((address_space(1))) void*)g,
                                   (__attribute__((address_space(3))) void*)l, 16, 0, 0);
}

// ---------- fused prep: cvt x -> xb (padded bf16), w1 -> wb[tap][h][f] bf16, build WT ----------
__global__ __launch_bounds__(256) void k_prep(const float* __restrict__ x,
                                              const float* __restrict__ w1,
                                              unsigned short* __restrict__ xb,
                                              unsigned short* __restrict__ wb,
                                              unsigned short* __restrict__ WT) {
  __shared__ float Ls[FEATD * 3];
  const int tid = threadIdx.x;
  const int bx = blockIdx.x;
  if (bx < 1296) {
    // x path: row = b*162 + pr; pr 0 and 161 are zero pads
    const int idx = bx * 256 + tid;
    const int c = (idx & 255) * 8;
    const int row = idx >> 8;
    const int b = row / 162, pr = row - b * 162;
    unsigned short* o = xb + (size_t)row * FEATD + c;
    if (pr == 0 || pr == 161) {
      *(uint4*)o = make_uint4(0u, 0u, 0u, 0u);
    } else {
      const float* src = x + ((size_t)(b * TS + pr - 1)) * FEATD + c;
      float4 v0 = *(const float4*)src;
      float4 v1 = *(const float4*)(src + 4);
      unsigned short r[8] = {f2bf(v0.x), f2bf(v0.y), f2bf(v0.z), f2bf(v0.w),
                             f2bf(v1.x), f2bf(v1.y), f2bf(v1.z), f2bf(v1.w)};
      *(uint4*)o = *(const uint4*)r;
    }
  } else if (bx < 1808) {
    // w path: one h row per block, LDS-staged coalesced transpose
    const int h = bx - 1296;
    const float4* src = (const float4*)(w1 + (size_t)h * (FEATD * 3));
    for (int e = tid; e < FEATD * 3 / 4; e += 256) ((float4*)Ls)[e] = src[e];
    __syncthreads();
    for (int oc = tid; oc < 768; oc += 256) {
      const int tap = oc >> 8;
      const int f0 = (oc & 255) * 8;
      unsigned short r[8];
      #pragma unroll
      for (int i = 0; i < 8; ++i) r[i] = f2bf(Ls[(f0 + i) * 3 + tap]);
      *(uint4*)&wb[((size_t)tap * HID + h) * FEATD + f0] = *(const uint4*)r;
    }
  } else {
    // WT build: WT[g][d+160][tau] bf16, rows d<0 zero
    const int idx = (bx - 1808) * 256 + tid;   // 600*256
    const int tau = idx % 160;
    const int dd = (idx / 160) % 320;
    const int g = idx / (160 * 320);
    float w = 0.f;
    if (dd >= 160) {
      const int d = dd - 160;
      const int k0 = (g == 0) ? 0 : (g == 1 ? 8 : 24);
      const int k1 = (g == 0) ? 8 : (g == 1 ? 24 : 32);
      for (int k = k0; k < k1; ++k) {
        float p = (float)(d * k) / 31.0f;
        float a = fabsf(p - (float)tau);
        w += fmaxf(0.f, 1.f - a);
      }
      w *= (g == 1) ? 0.0625f : 0.125f;
    }
    WT[idx] = f2bf(w);
  }
}

// ---------- conv1d as bf16 MFMA GEMM: tap-shared staging, bf16 partial out ----------
__global__ __launch_bounds__(256, 3) void k_conv_mfma(const unsigned short* __restrict__ xb,
                                                      const unsigned short* __restrict__ wb,
                                                      unsigned short* __restrict__ part) {
  const int bb = blockIdx.x;
  const int h0 = blockIdx.y * 64;
  const int kz = blockIdx.z;
  const int tid = threadIdx.x;
  const int wid = tid >> 6, lane = tid & 63;

  __shared__ unsigned short Alds[162 * 64];
  __shared__ unsigned short Blds[3 * 64 * 64];

  const unsigned short* xbb = xb + (size_t)bb * 162 * FEATD;
  const unsigned short* wbb = wb + (size_t)h0 * FEATD;

  f32x4 acc[5][2] = {};
  const int wr = wid >> 1, wc = wid & 1;

  for (int s = 0; s < 4; ++s) {
    const int f0 = kz * 256 + s * 64;
    #pragma unroll
    for (int is = 0; is < 5; ++is) {
      const int ci = is * 256 + wid * 64 + lane;
      const int row = ci >> 3, c = ci & 7;
      gload16(xbb + (size_t)row * FEATD + f0 + ((c ^ (row & 7)) << 3),
              (char*)Alds + (size_t)(is * 256 + wid * 64) * 16);
    }
    #pragma unroll
    for (int is = 0; is < 6; ++is) {
      const int ci = is * 256 + wid * 64 + lane;
      const int tap = ci >> 9, rr = (ci >> 3) & 63, c = ci & 7;
      gload16(wbb + (size_t)tap * (HID * FEATD) + (size_t)rr * FEATD + f0 + ((c ^ (rr & 7)) << 3),
              (char*)Blds + (size_t)(is * 256 + wid * 64) * 16);
    }
    if (tid < 16) {
      const int row = 160 + (tid >> 3), c = tid & 7;
      uint4 v = *(const uint4*)(xbb + (size_t)row * FEATD + f0 + ((c ^ (row & 7)) << 3));
      *(uint4*)((char*)Alds + row * 128 + c * 16) = v;
    }
    __syncthreads();

    #pragma unroll
    for (int tap = 0; tap < 3; ++tap) {
      #pragma unroll
      for (int kk = 0; kk < 2; ++kk) {
        const int cread = kk * 4 + (lane >> 4);
        bfrag bf0, bf1;
        {
          const int hh0 = wc * 32 + (lane & 15);
          const int hh1 = hh0 + 16;
          bf0 = *(const bfrag*)((char*)Blds + tap * 8192 + hh0 * 128 + ((cread ^ (hh0 & 7)) << 4));
          bf1 = *(const bfrag*)((char*)Blds + tap * 8192 + hh1 * 128 + ((cread ^ (hh1 & 7)) << 4));
        }
        #pragma unroll
        for (int mi = 0; mi < 5; ++mi) {
          const int rr = wr * 80 + mi * 16 + (lane & 15) + tap;
          bfrag af = *(const bfrag*)((char*)Alds + rr * 128 + ((cread ^ (rr & 7)) << 4));
          acc[mi][0] = __builtin_amdgcn_mfma_f32_16x16x32_bf16(af, bf0, acc[mi][0], 0, 0, 0);
          acc[mi][1] = __builtin_amdgcn_mfma_f32_16x16x32_bf16(af, bf1, acc[mi][1], 0, 0, 0);
        }
      }
    }
    __syncthreads();
  }

  unsigned short* pout = part + (size_t)kz * (NB * TS) * HID;
  #pragma unroll
  for (int mi = 0; mi < 5; ++mi) {
    const int r0 = bb * TS + wr * 80 + mi * 16 + (lane >> 4) * 4;
    #pragma unroll
    for (int ni = 0; ni < 2; ++ni) {
      const int c0 = h0 + wc * 32 + ni * 16 + (lane & 15);
      #pragma unroll
      for (int i = 0; i < 4; ++i)
        pout[(size_t)(r0 + i) * HID + c0] = f2bf(acc[mi][ni][i]);
    }
  }
}

// ---------- sum 8 bf16 K-split partials + bias + relu -> feat f32 ----------
__global__ __launch_bounds__(256) void k_bias_relu(const unsigned short* __restrict__ part,
                                                   const float* __restrict__ bias,
                                                   float* __restrict__ feat) {
  const int idx = blockIdx.x * 256 + threadIdx.x;   // 81920 threads, 8 f32 each
  const int h0 = (idx & 63) * 8;
  float a[8];
  {
    float4 b0 = *(const float4*)&bias[h0];
    float4 b1 = *(const float4*)&bias[h0 + 4];
    a[0] = b0.x; a[1] = b0.y; a[2] = b0.z; a[3] = b0.w;
    a[4] = b1.x; a[5] = b1.y; a[6] = b1.z; a[7] = b1.w;
  }
  #pragma unroll
  for (int kz = 0; kz < 8; ++kz) {
    uint4 v = *(const uint4*)&part[(size_t)kz * (NB * TS * HID) + (size_t)idx * 8];
    const unsigned short* s = (const unsigned short*)&v;
    #pragma unroll
    for (int k = 0; k < 8; ++k) a[k] += bf2f(s[k]);
  }
  float4 o0, o1;
  o0.x = fmaxf(a[0], 0.f); o0.y = fmaxf(a[1], 0.f); o0.z = fmaxf(a[2], 0.f); o0.w = fmaxf(a[3], 0.f);
  o1.x = fmaxf(a[4], 0.f); o1.y = fmaxf(a[5], 0.f); o1.z = fmaxf(a[6], 0.f); o1.w = fmaxf(a[7], 0.f);
  *(float4*)&feat[(size_t)idx * 8] = o0;
  *(float4*)&feat[(size_t)idx * 8 + 4] = o1;
}

// ---------- y_class + y_atn ----------
__global__ __launch_bounds__(256) void k_head(const float* __restrict__ feat,
                                              const float* __restrict__ wc,
                                              const float* __restrict__ wa,
                                              const float* __restrict__ ba,
                                              float* __restrict__ y_class,
                                              float* __restrict__ y_atn) {
  __shared__ float wcs[NC * HID];
  __shared__ float was[HID * 3];
  const int tid = threadIdx.x;
  for (int e = tid; e < NC * HID; e += 256) wcs[e] = wc[e];
  for (int e = tid; e < HID * 3; e += 256) was[e] = wa[e];
  __syncthreads();
  const int wave = blockIdx.x * 4 + (tid >> 6);
  const int lane = tid & 63;
  const int b = wave / TS, t = wave - b * TS;
  const float* frow = &feat[((size_t)b * TS + t) * HID];
  float fc[8], fm[8], fp[8];
  #pragma unroll
  for (int i2 = 0; i2 < 8; ++i2) {
    int h = lane + 64 * i2;
    fc[i2] = frow[h];
    fm[i2] = (t > 0)      ? frow[h - HID] : 0.f;
    fp[i2] = (t < TS - 1) ? frow[h + HID] : 0.f;
  }
  #pragma unroll 4
  for (int c = 0; c < NC; ++c) {
    float p = 0.f;
    #pragma unroll
    for (int i2 = 0; i2 < 8; ++i2) p += fc[i2] * wcs[c * HID + lane + 64 * i2];
    #pragma unroll
    for (int off = 32; off; off >>= 1) p += __shfl_xor(p, off);
    if (lane == 0) y_class[((size_t)b * NC + c) * TS + t] = p;
  }
  float p = 0.f;
  #pragma unroll
  for (int i2 = 0; i2 < 8; ++i2) {
    int h = lane + 64 * i2;
    p += fm[i2] * was[h * 3 + 0] + fc[i2] * was[h * 3 + 1] + fp[i2] * was[h * 3 + 2];
  }
  #pragma unroll
  for (int off = 32; off; off >>= 1) p += __shfl_xor(p, off);
  if (lane == 0) y_atn[b * TS + t] = p + ba[0];
}

// ---------- fused tail: bmn MFMA (y<3) + attention pooling fg (y==3) ----------
__global__ __launch_bounds__(256) void k_tail(const float* __restrict__ y_class,
                                              const unsigned short* __restrict__ WT,
                                              const float* __restrict__ feat,
                                              const float* __restrict__ y_atn,
                                              const float* __restrict__ wc,
                                              float* __restrict__ y_fg,
                                              float* __restrict__ bmn) {
  __shared__ char Tlds[64000 + 65536];
  const int tid = threadIdx.x;

  if (blockIdx.y == 3) {
    if (blockIdx.x >= 8) return;
    const int b = blockIdx.x;
    float* sig = (float*)Tlds;
    float* red = sig + TS;
    float* xfg = red + 8;
    float s = 0.f;
    if (tid < TS) { s = 1.f / (1.f + expf(-y_atn[b * TS + tid])); sig[tid] = s; }
    float r = s;
    #pragma unroll
    for (int off = 32; off; off >>= 1) r += __shfl_xor(r, off);
    if ((tid & 63) == 0) red[tid >> 6] = r;
    __syncthreads();
    const float inv = 1.f / (red[0] + red[1] + red[2] + red[3] + 1e-8f);
    for (int h = tid; h < HID; h += 256) {
      float a = 0.f;
      for (int t = 0; t < TS; ++t) a += sig[t] * feat[((size_t)b * TS + t) * HID + h];
      xfg[h] = a * inv;
    }
    __syncthreads();
    const int wv = tid >> 6, lane = tid & 63;
    for (int c = wv; c < NC; c += 4) {
      float p = 0.f;
      #pragma unroll
      for (int i2 = 0; i2 < 8; ++i2) {
        int h = lane + 64 * i2;
        p += wc[c * HID + h] * xfg[h];
      }
      #pragma unroll
      for (int off = 32; off; off >>= 1) p += __shfl_xor(p, off);
      if (lane == 0) y_fg[b * NC + c] = p;
    }
    return;
  }

  // ---- bmn path: per-(i,g) 160x160x160 bf16 GEMM ----
  char* Alds = Tlds;            // 160 rows x 400 B
  char* Wlds = Tlds + 64000;    // 4096 chunks x 16 B
  const int i = blockIdx.x;
  const int g = blockIdx.y;
  const int wid = tid >> 6, lane = tid & 63;

  // stage W via global_load_lds (rows clamped; pad chunks read row base)
  const char* wtb = (const char*)WT + (size_t)g * 102400 + (size_t)(160 - i) * 320;
  #pragma unroll
  for (int it = 0; it < 16; ++it) {
    const int idx = it * 256 + tid;
    int row = idx / 25, c = idx - row * 25;
    if (row > 159) row = 159;
    if (c > 19) c = 0;
    gload16(wtb + (size_t)row * 320 + c * 16, Wlds + (size_t)idx * 16);
  }
  // stage A: read y_class f32 (L2-hot), cvt bf16, swizzle-free 400-B-stride rows
  for (int e = 0; e < 13; ++e) {
    const int ci = e * 256 + tid;
    if (ci < 3200) {
      const int row = ci / 20, c = ci - row * 20;
      const int tb = i + c * 8;
      const float* yr = y_class + (size_t)row * TS;
      unsigned short r8[8];
      #pragma unroll
      for (int k = 0; k < 8; ++k) {
        const int t = tb + k;
        r8[k] = (t < TS) ? f2bf(yr[t]) : (unsigned short)0;
      }
      *(uint4*)(Alds + (size_t)row * 400 + c * 16) = *(const uint4*)r8;
    }
  }
  __syncthreads();

  const int wr = wid >> 1, wcq = wid & 1;
  f32x4 acc[5][5] = {};

  #pragma unroll
  for (int ks = 0; ks < 5; ++ks) {
    const int cc = ks * 4 + (lane >> 4);
    bfrag bfr[5];
    #pragma unroll
    for (int nf = 0; nf < 5; ++nf) {
      const int j = wcq * 80 + nf * 16 + (lane & 15);
      bfr[nf] = *(const bfrag*)(Wlds + (size_t)j * 400 + cc * 16);
    }
    #pragma unroll
    for (int mf = 0; mf < 5; ++mf) {
      const int r = wr * 80 + mf * 16 + (lane & 15);
      bfrag af = *(const bfrag*)(Alds + (size_t)r * 400 + cc * 16);
      #pragma unroll
      for (int nf = 0; nf < 5; ++nf)
        acc[mf][nf] = __builtin_amdgcn_mfma_f32_16x16x32_bf16(af, bfr[nf], acc[mf][nf], 0, 0, 0);
    }
  }

  #pragma unroll
  for (int mf = 0; mf < 5; ++mf) {
    const int r0 = wr * 80 + mf * 16 + (lane >> 4) * 4;
    #pragma unroll
    for (int reg = 0; reg < 4; ++reg) {
      const int r = r0 + reg;
      const int b = r / 20, c = r - b * 20;
      float* base = bmn + (((size_t)(b * 60 + g * 20 + c) * TS) + i) * TS;
      #pragma unroll
      for (int nf = 0; nf < 5; ++nf) {
        const int j = wcq * 80 + nf * 16 + (lane & 15);
        base[j] = acc[mf][nf][reg];
      }
    }
  }
}

extern "C" void kernel_launch(void* const* d_in, const int* in_sizes, int n_in,
                              void* d_out, int out_size, void* d_ws, size_t ws_size,
                              hipStream_t stream) {
  const float* x  = (const float*)d_in[0];
  const float* w1 = (const float*)d_in[2];
  const float* b1 = (const float*)d_in[3];
  const float* wc = (const float*)d_in[4];
  const float* wa = (const float*)d_in[5];
  const float* ba = (const float*)d_in[6];

  float* out     = (float*)d_out;
  float* y_class = out;                            // [8,20,160]
  float* y_fg    = out + NB * NC * TS;             // [8,20,1]
  float* bmn     = out + NB * NC * TS + NB * NC;   // [8,60,160,160]

  unsigned short* part = (unsigned short*)d_ws;                 // 8*1280*512 bf16
  float* feat  = (float*)((char*)d_ws + (size_t)8 * NB * TS * HID * 2);  // 1280*512 f32
  float* y_atn = feat + NB * TS * HID;                          // 1280 f32 (pad 2048)
  unsigned short* xb = (unsigned short*)(y_atn + 2048);         // 8*162*2048 bf16
  unsigned short* wb = xb + (size_t)NB * 162 * FEATD;           // 3*512*2048 bf16
  unsigned short* WT = wb + (size_t)3 * HID * FEATD;            // 3*320*160 bf16

  k_prep<<<1808 + 600, 256, 0, stream>>>(x, w1, xb, wb, WT);
  k_conv_mfma<<<dim3(8, 8, 8), 256, 0, stream>>>(xb, wb, part);
  k_bias_relu<<<320, 256, 0, stream>>>(part, b1, feat);
  k_head<<<320, 256, 0, stream>>>(feat, wc, wa, ba, y_class, y_atn);
  k_tail<<<dim3(160, 4), 256, 0, stream>>>(y_class, WT, feat, y_atn, wc, y_fg, bmn);
}

// Round 6
// 72.384 us; speedup vs baseline: 3.0589x; 1.0510x over previous
//
#include <hip/hip_runtime.h>
#include <math.h>

#define TS 160
#define FEATD 2048
#define HID 512
#define NC 20
#define NB 8
#define KZ 16

typedef __attribute__((ext_vector_type(8))) short bfrag;
typedef __attribute__((ext_vector_type(4))) float f32x4;

static __device__ __forceinline__ unsigned short f2bf(float f) {
  unsigned int u = __float_as_uint(f);
  unsigned int r = (u + 0x7FFFu + ((u >> 16) & 1u)) >> 16;
  return (unsigned short)r;
}
static __device__ __forceinline__ float bf2f(unsigned short s) {
  return __uint_as_float(((unsigned int)s) << 16);
}

static __device__ __forceinline__ void gload16(const void* g, void* l) {
  __builtin_amdgcn_global_load_lds((const __attribute__((address_space(1))) void*)g,
                                   (__attribute__((address_space(3))) void*)l, 16, 0, 0);
}

// ---------- fused prep: cvt x->xb (padded bf16), w1->wb[tap][h][f], build WT, seed y_atn ----------
__global__ __launch_bounds__(256) void k_prep(const float* __restrict__ x,
                                              const float* __restrict__ w1,
                                              const float* __restrict__ ba,
                                              unsigned short* __restrict__ xb,
                                              unsigned short* __restrict__ wb,
                                              unsigned short* __restrict__ WT,
                                              float* __restrict__ y_atn) {
  __shared__ float Ls[FEATD * 3];
  const int tid = threadIdx.x;
  const int bx = blockIdx.x;
  if (bx < 1296) {
    const int idx = bx * 256 + tid;
    const int c = (idx & 255) * 8;
    const int row = idx >> 8;
    const int b = row / 162, pr = row - b * 162;
    unsigned short* o = xb + (size_t)row * FEATD + c;
    if (pr == 0 || pr == 161) {
      *(uint4*)o = make_uint4(0u, 0u, 0u, 0u);
    } else {
      const float* src = x + ((size_t)(b * TS + pr - 1)) * FEATD + c;
      float4 v0 = *(const float4*)src;
      float4 v1 = *(const float4*)(src + 4);
      unsigned short r[8] = {f2bf(v0.x), f2bf(v0.y), f2bf(v0.z), f2bf(v0.w),
                             f2bf(v1.x), f2bf(v1.y), f2bf(v1.z), f2bf(v1.w)};
      *(uint4*)o = *(const uint4*)r;
    }
  } else if (bx < 1808) {
    const int h = bx - 1296;
    const float4* src = (const float4*)(w1 + (size_t)h * (FEATD * 3));
    for (int e = tid; e < FEATD * 3 / 4; e += 256) ((float4*)Ls)[e] = src[e];
    __syncthreads();
    for (int oc = tid; oc < 768; oc += 256) {
      const int tap = oc >> 8;
      const int f0 = (oc & 255) * 8;
      unsigned short r[8];
      #pragma unroll
      for (int i = 0; i < 8; ++i) r[i] = f2bf(Ls[(f0 + i) * 3 + tap]);
      *(uint4*)&wb[((size_t)tap * HID + h) * FEATD + f0] = *(const uint4*)r;
    }
  } else if (bx < 2408) {
    // WT[g][d+160][tau] bf16, rows d<0 zero
    const int idx = (bx - 1808) * 256 + tid;
    const int tau = idx % 160;
    const int dd = (idx / 160) % 320;
    const int g = idx / (160 * 320);
    float w = 0.f;
    if (dd >= 160) {
      const int d = dd - 160;
      const int k0 = (g == 0) ? 0 : (g == 1 ? 8 : 24);
      const int k1 = (g == 0) ? 8 : (g == 1 ? 24 : 32);
      for (int k = k0; k < k1; ++k) {
        float p = (float)(d * k) / 31.0f;
        float a = fabsf(p - (float)tau);
        w += fmaxf(0.f, 1.f - a);
      }
      w *= (g == 1) ? 0.0625f : 0.125f;
    }
    WT[idx] = f2bf(w);
  } else {
    const int idx = (bx - 2408) * 256 + tid;
    if (idx < NB * TS) y_atn[idx] = ba[0];
  }
}

// ---------- conv1d as bf16 MFMA GEMM: wave tile 80x64, block 160x128, K-split 16 ----------
__global__ __launch_bounds__(256, 2) void k_conv_mfma(const unsigned short* __restrict__ xb,
                                                      const unsigned short* __restrict__ wb,
                                                      unsigned short* __restrict__ part) {
  const int bb = blockIdx.x;
  const int hq = blockIdx.y;           // h-base = hq*128
  const int kz = blockIdx.z;           // f-base = kz*128
  const int tid = threadIdx.x;
  const int wid = tid >> 6, lane = tid & 63;

  __shared__ unsigned short Alds[162 * 64];      // [row][64 f], chunk-swizzled
  __shared__ unsigned short Blds[3 * 128 * 64];  // [tap][h][64 f], chunk-swizzled

  const unsigned short* xbb = xb + (size_t)bb * 162 * FEATD;

  f32x4 acc[5][4] = {};
  const int wr = wid >> 1, wc = wid & 1;

  for (int s = 0; s < 2; ++s) {
    const int f0 = kz * 128 + s * 64;
    // A rows 0..159 (5 full issues), content[row][c] = global chunk c^(row&7)
    #pragma unroll
    for (int is = 0; is < 5; ++is) {
      const int ci = is * 256 + wid * 64 + lane;
      const int row = ci >> 3, c = ci & 7;
      gload16(xbb + (size_t)row * FEATD + f0 + ((c ^ (row & 7)) << 3),
              (char*)Alds + (size_t)(is * 256 + wid * 64) * 16);
    }
    // B: 3 taps x 128 rows x 8 chunks = 3072 chunks = 12 issues
    #pragma unroll
    for (int is = 0; is < 12; ++is) {
      const int ci = is * 256 + wid * 64 + lane;
      const int tap = ci >> 10, rr = (ci >> 3) & 127, c = ci & 7;
      gload16(wb + ((size_t)(tap * HID + hq * 128 + rr)) * FEATD + f0 + ((c ^ (rr & 7)) << 3),
              (char*)Blds + (size_t)(is * 256 + wid * 64) * 16);
    }
    // A tail rows 160,161
    if (tid < 16) {
      const int row = 160 + (tid >> 3), c = tid & 7;
      uint4 v = *(const uint4*)(xbb + (size_t)row * FEATD + f0 + ((c ^ (row & 7)) << 3));
      *(uint4*)((char*)Alds + row * 128 + c * 16) = v;
    }
    __syncthreads();

    #pragma unroll
    for (int tap = 0; tap < 3; ++tap) {
      #pragma unroll
      for (int kk = 0; kk < 2; ++kk) {
        const int cc = kk * 4 + (lane >> 4);
        bfrag bfr[4];
        #pragma unroll
        for (int nf = 0; nf < 4; ++nf) {
          const int hh = wc * 64 + nf * 16 + (lane & 15);
          bfr[nf] = *(const bfrag*)((char*)Blds + (size_t)(((tap * 128 + hh) * 8) + (cc ^ (hh & 7))) * 16);
        }
        #pragma unroll
        for (int mi = 0; mi < 5; ++mi) {
          const int rr = wr * 80 + mi * 16 + (lane & 15) + tap;
          bfrag af = *(const bfrag*)((char*)Alds + (size_t)((rr * 8) + (cc ^ (rr & 7))) * 16);
          #pragma unroll
          for (int nf = 0; nf < 4; ++nf)
            acc[mi][nf] = __builtin_amdgcn_mfma_f32_16x16x32_bf16(af, bfr[nf], acc[mi][nf], 0, 0, 0);
        }
      }
    }
    __syncthreads();
  }

  unsigned short* pout = part + (size_t)kz * (NB * TS) * HID;
  #pragma unroll
  for (int mi = 0; mi < 5; ++mi) {
    const int r0 = bb * TS + wr * 80 + mi * 16 + (lane >> 4) * 4;
    #pragma unroll
    for (int nf = 0; nf < 4; ++nf) {
      const int c0 = hq * 128 + wc * 64 + nf * 16 + (lane & 15);
      #pragma unroll
      for (int i = 0; i < 4; ++i)
        pout[(size_t)(r0 + i) * HID + c0] = f2bf(acc[mi][nf][i]);
    }
  }
}

// ---------- fused: sum partials + bias + relu -> feat; y_class; y_atn tap-scatter ----------
__global__ __launch_bounds__(256) void k_feat_head(const unsigned short* __restrict__ part,
                                                   const float* __restrict__ b1,
                                                   const float* __restrict__ wc,
                                                   const float* __restrict__ wa,
                                                   float* __restrict__ feat,
                                                   float* __restrict__ y_class,
                                                   float* __restrict__ y_atn) {
  const int bt = blockIdx.x;            // 0..1279 = b*160 + t
  const int tid = threadIdx.x;
  __shared__ float fr[HID];
  __shared__ float sred[4][3];
  const int h0 = tid * 2;
  float a0 = b1[h0], a1 = b1[h0 + 1];
  #pragma unroll
  for (int kz = 0; kz < KZ; ++kz) {
    unsigned int v = *(const unsigned int*)&part[(size_t)kz * (NB * TS * HID) + (size_t)bt * HID + h0];
    a0 += bf2f((unsigned short)(v & 0xffff));
    a1 += bf2f((unsigned short)(v >> 16));
  }
  a0 = fmaxf(a0, 0.f);
  a1 = fmaxf(a1, 0.f);
  float2 fo; fo.x = a0; fo.y = a1;
  *(float2*)&feat[(size_t)bt * HID + h0] = fo;
  fr[h0] = a0; fr[h0 + 1] = a1;
  // y_atn tap partials (this row's contribution to t+1 / t / t-1)
  float s0 = a0 * wa[h0 * 3 + 0] + a1 * wa[h0 * 3 + 3];
  float s1 = a0 * wa[h0 * 3 + 1] + a1 * wa[h0 * 3 + 4];
  float s2 = a0 * wa[h0 * 3 + 2] + a1 * wa[h0 * 3 + 5];
  #pragma unroll
  for (int off = 32; off; off >>= 1) {
    s0 += __shfl_xor(s0, off);
    s1 += __shfl_xor(s1, off);
    s2 += __shfl_xor(s2, off);
  }
  const int wv = tid >> 6, lane = tid & 63;
  if (lane == 0) { sred[wv][0] = s0; sred[wv][1] = s1; sred[wv][2] = s2; }
  __syncthreads();
  const int b = bt / TS, t = bt - b * TS;
  for (int c = wv; c < NC; c += 4) {
    float p = 0.f;
    #pragma unroll
    for (int i2 = 0; i2 < 8; ++i2) p += fr[lane + 64 * i2] * wc[c * HID + lane + 64 * i2];
    #pragma unroll
    for (int off = 32; off; off >>= 1) p += __shfl_xor(p, off);
    if (lane == 0) y_class[((size_t)b * NC + c) * TS + t] = p;
  }
  if (tid == 0) {
    float S0 = sred[0][0] + sred[1][0] + sred[2][0] + sred[3][0];
    float S1 = sred[0][1] + sred[1][1] + sred[2][1] + sred[3][1];
    float S2 = sred[0][2] + sred[1][2] + sred[2][2] + sred[3][2];
    atomicAdd(&y_atn[bt], S1);
    if (t < TS - 1) atomicAdd(&y_atn[bt + 1], S0);
    if (t > 0)      atomicAdd(&y_atn[bt - 1], S2);
  }
}

// ---------- fused tail: bmn MFMA (y<3) + attention pooling fg (y==3) ----------
__global__ __launch_bounds__(256) void k_tail(const float* __restrict__ y_class,
                                              const unsigned short* __restrict__ WT,
                                              const float* __restrict__ feat,
                                              const float* __restrict__ y_atn,
                                              const float* __restrict__ wc,
                                              float* __restrict__ y_fg,
                                              float* __restrict__ bmn) {
  __shared__ char Tlds[64000 + 65536];
  const int tid = threadIdx.x;

  if (blockIdx.y == 3) {
    if (blockIdx.x >= NB) return;
    const int b = blockIdx.x;
    float* sig = (float*)Tlds;
    float* red = sig + TS;
    float* xfg = red + 8;
    float s = 0.f;
    if (tid < TS) { s = 1.f / (1.f + expf(-y_atn[b * TS + tid])); sig[tid] = s; }
    float r = s;
    #pragma unroll
    for (int off = 32; off; off >>= 1) r += __shfl_xor(r, off);
    if ((tid & 63) == 0) red[tid >> 6] = r;
    __syncthreads();
    const float inv = 1.f / (red[0] + red[1] + red[2] + red[3] + 1e-8f);
    for (int h = tid; h < HID; h += 256) {
      float a = 0.f;
      for (int t = 0; t < TS; ++t) a += sig[t] * feat[((size_t)b * TS + t) * HID + h];
      xfg[h] = a * inv;
    }
    __syncthreads();
    const int wv = tid >> 6, lane = tid & 63;
    for (int c = wv; c < NC; c += 4) {
      float p = 0.f;
      #pragma unroll
      for (int i2 = 0; i2 < 8; ++i2) {
        int h = lane + 64 * i2;
        p += wc[c * HID + h] * xfg[h];
      }
      #pragma unroll
      for (int off = 32; off; off >>= 1) p += __shfl_xor(p, off);
      if (lane == 0) y_fg[b * NC + c] = p;
    }
    return;
  }

  // ---- bmn path: per-(i,g) 160x160x160 bf16 GEMM ----
  char* Alds = Tlds;            // 160 rows x 400 B
  char* Wlds = Tlds + 64000;    // 4096 chunks x 16 B
  const int i = blockIdx.x;
  const int g = blockIdx.y;
  const int wid = tid >> 6, lane = tid & 63;

  const char* wtb = (const char*)WT + (size_t)g * 102400 + (size_t)(160 - i) * 320;
  #pragma unroll
  for (int it = 0; it < 16; ++it) {
    const int idx = it * 256 + tid;
    int row = idx / 25, c = idx - row * 25;
    if (row > 159) row = 159;
    if (c > 19) c = 0;
    gload16(wtb + (size_t)row * 320 + c * 16, Wlds + (size_t)idx * 16);
  }
  for (int e = 0; e < 13; ++e) {
    const int ci = e * 256 + tid;
    if (ci < 3200) {
      const int row = ci / 20, c = ci - row * 20;
      const int tb = i + c * 8;
      const float* yr = y_class + (size_t)row * TS;
      unsigned short r8[8];
      #pragma unroll
      for (int k = 0; k < 8; ++k) {
        const int t = tb + k;
        r8[k] = (t < TS) ? f2bf(yr[t]) : (unsigned short)0;
      }
      *(uint4*)(Alds + (size_t)row * 400 + c * 16) = *(const uint4*)r8;
    }
  }
  __syncthreads();

  const int wr = wid >> 1, wcq = wid & 1;
  f32x4 acc[5][5] = {};

  #pragma unroll
  for (int ks = 0; ks < 5; ++ks) {
    const int cc = ks * 4 + (lane >> 4);
    bfrag bfr[5];
    #pragma unroll
    for (int nf = 0; nf < 5; ++nf) {
      const int j = wcq * 80 + nf * 16 + (lane & 15);
      bfr[nf] = *(const bfrag*)(Wlds + (size_t)j * 400 + cc * 16);
    }
    #pragma unroll
    for (int mf = 0; mf < 5; ++mf) {
      const int r = wr * 80 + mf * 16 + (lane & 15);
      bfrag af = *(const bfrag*)(Alds + (size_t)r * 400 + cc * 16);
      #pragma unroll
      for (int nf = 0; nf < 5; ++nf)
        acc[mf][nf] = __builtin_amdgcn_mfma_f32_16x16x32_bf16(af, bfr[nf], acc[mf][nf], 0, 0, 0);
    }
  }

  #pragma unroll
  for (int mf = 0; mf < 5; ++mf) {
    const int r0 = wr * 80 + mf * 16 + (lane >> 4) * 4;
    #pragma unroll
    for (int reg = 0; reg < 4; ++reg) {
      const int r = r0 + reg;
      const int b = r / 20, c = r - b * 20;
      float* base = bmn + (((size_t)(b * 60 + g * 20 + c) * TS) + i) * TS;
      #pragma unroll
      for (int nf = 0; nf < 5; ++nf) {
        const int j = wcq * 80 + nf * 16 + (lane & 15);
        base[j] = acc[mf][nf][reg];
      }
    }
  }
}

extern "C" void kernel_launch(void* const* d_in, const int* in_sizes, int n_in,
                              void* d_out, int out_size, void* d_ws, size_t ws_size,
                              hipStream_t stream) {
  const float* x  = (const float*)d_in[0];
  const float* w1 = (const float*)d_in[2];
  const float* b1 = (const float*)d_in[3];
  const float* wc = (const float*)d_in[4];
  const float* wa = (const float*)d_in[5];
  const float* ba = (const float*)d_in[6];

  float* out     = (float*)d_out;
  float* y_class = out;                            // [8,20,160]
  float* y_fg    = out + NB * NC * TS;             // [8,20,1]
  float* bmn     = out + NB * NC * TS + NB * NC;   // [8,60,160,160]

  unsigned short* part = (unsigned short*)d_ws;                       // KZ*1280*512 bf16
  float* feat  = (float*)((char*)d_ws + (size_t)KZ * NB * TS * HID * 2);  // 1280*512 f32
  float* y_atn = feat + NB * TS * HID;                                // 1280 f32 (pad 2048)
  unsigned short* xb = (unsigned short*)(y_atn + 2048);               // 8*162*2048 bf16
  unsigned short* wb = xb + (size_t)NB * 162 * FEATD;                 // 3*512*2048 bf16
  unsigned short* WT = wb + (size_t)3 * HID * FEATD;                  // 3*320*160 bf16

  k_prep<<<2413, 256, 0, stream>>>(x, w1, ba, xb, wb, WT, y_atn);
  k_conv_mfma<<<dim3(8, 4, KZ), 256, 0, stream>>>(xb, wb, part);
  k_feat_head<<<NB * TS, 256, 0, stream>>>(part, b1, wc, wa, feat, y_class, y_atn);
  k_tail<<<dim3(160, 4), 256, 0, stream>>>(y_class, WT, feat, y_atn, wc, y_fg, bmn);
}